// Round 1
// baseline (659.996 us; speedup 1.0000x reference)
//
#include <hip/hip_runtime.h>

// Problem constants (from reference): B=128, N=512, H=256, F_JET=8, gin=776.
#define B_   128
#define N_   512
#define H_   256
#define FJ   8
#define ROWS (B_ * N_)          // 65536 flattened vertex rows
#define NEGV (-1e9f)

typedef __attribute__((ext_vector_type(8))) __bf16 b16x8;   // one MFMA A/B fragment (4 VGPRs)
typedef __attribute__((ext_vector_type(4))) float  f32x4;   // one MFMA C/D fragment

static __device__ inline f32x4 MFMA(b16x8 a, b16x8 b, f32x4 c) {
  return __builtin_amdgcn_mfma_f32_16x16x32_bf16(a, b, c, 0, 0, 0);
}

// ---------------------------------------------------------------------------
// Prep: transpose/convert weights once per launch.
//  WaT_hi/lo[d][k] = split(Wa[k][d])        (256x256)
//  WmT[d][k]       = bf16(Wm[k][d])         (256x256)
//  WzrT[n][k]      = bf16(W{z|r}[row(k)][n']) n<256 -> Wz, else Wr (512x512)
//                    row(k) = k<256 ? k : 520+(k-256)   (msg part / h part)
//  WhcT[n][k]      = bf16(Wh[row(k)][n])    (256x512)
// ---------------------------------------------------------------------------
__global__ void k_prep(const float* __restrict__ Wa, const float* __restrict__ Wm,
                       const float* __restrict__ Wz, const float* __restrict__ Wr,
                       const float* __restrict__ Wh,
                       __bf16* __restrict__ WaT_hi, __bf16* __restrict__ WaT_lo,
                       __bf16* __restrict__ WmT,    __bf16* __restrict__ WzrT,
                       __bf16* __restrict__ WhcT) {
  int idx = blockIdx.x * 256 + threadIdx.x;
  if (idx < 65536) {
    int d = idx >> 8, k = idx & 255;
    float w = Wa[k * 256 + d];
    __bf16 hb = (__bf16)w;
    WaT_hi[d * 256 + k] = hb;
    WaT_lo[d * 256 + k] = (__bf16)(w - (float)hb);
  } else if (idx < 131072) {
    int t = idx - 65536;
    int d = t >> 8, k = t & 255;
    WmT[d * 256 + k] = (__bf16)Wm[k * 256 + d];
  } else if (idx < 131072 + 262144) {
    int t = idx - 131072;
    int n = t >> 9, k = t & 511;
    const float* src = (n < 256) ? Wz : Wr;
    int np  = n & 255;
    int row = (k < 256) ? k : (264 + k);   // 520 + (k - 256)
    WzrT[n * 512 + k] = (__bf16)src[row * 256 + np];
  } else {
    int t = idx - (131072 + 262144);       // < 131072
    int n = t >> 9, k = t & 511;
    int row = (k < 256) ? k : (264 + k);
    WhcT[n * 512 + k] = (__bf16)Wh[row * 256 + n];
  }
}

// h_mean[b][d] = mean_n h[b][n][d]
__global__ void k_hmean(const float* __restrict__ h, float* __restrict__ hmean) {
  int b = blockIdx.x, d = threadIdx.x;
  const float* p = h + (size_t)b * N_ * H_ + d;
  float s = 0.f;
  #pragma unroll 8
  for (int n = 0; n < N_; ++n) s += p[n * H_];
  hmean[b * H_ + d] = s * (1.f / N_);
}

// Per-batch GRU constants: c_*[b][d] = bias[d] + h_mean[b]·W*[256:512,d] + jets[b]·W*[512:520,d]
__global__ void k_cvec(const float* __restrict__ hmean, const float* __restrict__ jets,
                       const float* __restrict__ Wz, const float* __restrict__ Wr,
                       const float* __restrict__ Wh,
                       const float* __restrict__ bz, const float* __restrict__ br,
                       const float* __restrict__ bh,
                       float* __restrict__ cz, float* __restrict__ cr, float* __restrict__ ch) {
  __shared__ float hm[H_];
  __shared__ float jt[FJ];
  int b = blockIdx.x, d = threadIdx.x;
  hm[d] = hmean[b * H_ + d];
  if (d < FJ) jt[d] = jets[b * FJ + d];
  __syncthreads();
  float az = bz[d], ar = br[d], ah = bh[d];
  #pragma unroll 4
  for (int k = 0; k < H_; ++k) {
    float m = hm[k];
    az += m * Wz[(256 + k) * 256 + d];
    ar += m * Wr[(256 + k) * 256 + d];
    ah += m * Wh[(256 + k) * 256 + d];
  }
  #pragma unroll
  for (int f = 0; f < FJ; ++f) {
    float j = jt[f];
    az += j * Wz[(512 + f) * 256 + d];
    ar += j * Wr[(512 + f) * 256 + d];
    ah += j * Wh[(512 + f) * 256 + d];
  }
  cz[b * H_ + d] = az;
  cr[b * H_ + d] = ar;
  ch[b * H_ + d] = ah;
}

// ---------------------------------------------------------------------------
// q = h @ Wa + ba, computed accurately via 3-term bf16 split (hi*hi+hi*lo+lo*hi).
// Tile 128x128, BK=32, 4 waves (2x2), each wave 64x64 (4x4 frags). fp32 out.
// ---------------------------------------------------------------------------
__global__ __launch_bounds__(256) void k_gemm_q(
    const float* __restrict__ h, const __bf16* __restrict__ WaT_hi,
    const __bf16* __restrict__ WaT_lo, const float* __restrict__ ba,
    float* __restrict__ q) {
  __shared__ __bf16 Ahi[128][40], Alo[128][40], Bhi[128][40], Blo[128][40];
  const int tid = threadIdx.x, lane = tid & 63, wave = tid >> 6;
  const int g = lane >> 4, m16 = lane & 15;
  const int wr = (wave >> 1) * 64, wc = (wave & 1) * 64;
  const int m0 = blockIdx.y * 128, n0 = blockIdx.x * 128;
  f32x4 acc[4][4] = {};
  for (int k0 = 0; k0 < 256; k0 += 32) {
    __syncthreads();
    #pragma unroll
    for (int i = 0; i < 2; ++i) {
      int c = tid + i * 256;                // 512 chunks of 8 elements
      int row = c >> 2, kc = (c & 3) * 8;
      const float* p = h + (size_t)(m0 + row) * 256 + k0 + kc;
      f32x4 v0 = *(const f32x4*)p;
      f32x4 v1 = *(const f32x4*)(p + 4);
      b16x8 hv, lv;
      #pragma unroll
      for (int e = 0; e < 4; ++e) {
        __bf16 h0 = (__bf16)v0[e], h1 = (__bf16)v1[e];
        hv[e] = h0; hv[4 + e] = h1;
        lv[e]     = (__bf16)(v0[e] - (float)h0);
        lv[4 + e] = (__bf16)(v1[e] - (float)h1);
      }
      *(b16x8*)&Ahi[row][kc] = hv;
      *(b16x8*)&Alo[row][kc] = lv;
      size_t boff = (size_t)(n0 + row) * 256 + k0 + kc;
      *(b16x8*)&Bhi[row][kc] = *(const b16x8*)(WaT_hi + boff);
      *(b16x8*)&Blo[row][kc] = *(const b16x8*)(WaT_lo + boff);
    }
    __syncthreads();
    b16x8 ah[4], al[4], bh4[4], bl4[4];
    #pragma unroll
    for (int mi = 0; mi < 4; ++mi) {
      ah[mi] = *(const b16x8*)&Ahi[wr + mi * 16 + m16][8 * g];
      al[mi] = *(const b16x8*)&Alo[wr + mi * 16 + m16][8 * g];
    }
    #pragma unroll
    for (int ni = 0; ni < 4; ++ni) {
      bh4[ni] = *(const b16x8*)&Bhi[wc + ni * 16 + m16][8 * g];
      bl4[ni] = *(const b16x8*)&Blo[wc + ni * 16 + m16][8 * g];
    }
    #pragma unroll
    for (int mi = 0; mi < 4; ++mi)
      #pragma unroll
      for (int ni = 0; ni < 4; ++ni) {
        acc[mi][ni] = MFMA(ah[mi], bh4[ni], acc[mi][ni]);
        acc[mi][ni] = MFMA(ah[mi], bl4[ni], acc[mi][ni]);
        acc[mi][ni] = MFMA(al[mi], bh4[ni], acc[mi][ni]);
      }
  }
  #pragma unroll
  for (int mi = 0; mi < 4; ++mi)
    #pragma unroll
    for (int ni = 0; ni < 4; ++ni) {
      int gcol = n0 + wc + ni * 16 + m16;
      float bias = ba[gcol];
      #pragma unroll
      for (int r = 0; r < 4; ++r) {
        int grow = m0 + wr + mi * 16 + 4 * g + r;
        q[(size_t)grow * 256 + gcol] = acc[mi][ni][r] + bias;
      }
    }
}

// ---------------------------------------------------------------------------
// hmT[b][d][n] = bf16( (h[b] @ Wm + bm)^T ) computed as WmT @ h[b]^T.
// Stored transposed so attention PV B-fragments are k-contiguous.
// Tile 128x128, BK=64, single-term bf16.
// ---------------------------------------------------------------------------
__global__ __launch_bounds__(256) void k_gemm_hmT(
    const float* __restrict__ h, const __bf16* __restrict__ WmT,
    const float* __restrict__ bm, __bf16* __restrict__ hmT) {
  __shared__ __bf16 At[128][72], Bt[128][72];
  const int tid = threadIdx.x, lane = tid & 63, wave = tid >> 6;
  const int g = lane >> 4, m16 = lane & 15;
  const int wr = (wave >> 1) * 64, wc = (wave & 1) * 64;
  const int b = blockIdx.y;
  const int m0 = (blockIdx.x >> 2) * 128, n0 = (blockIdx.x & 3) * 128;
  const float* hb = h + (size_t)b * N_ * H_;
  f32x4 acc[4][4] = {};
  for (int k0 = 0; k0 < 256; k0 += 64) {
    __syncthreads();
    #pragma unroll
    for (int i = 0; i < 4; ++i) {
      int c = tid + i * 256;                // 1024 chunks of 8
      int row = c >> 3, kc = (c & 7) * 8;
      *(b16x8*)&At[row][kc] = *(const b16x8*)(WmT + (size_t)(m0 + row) * 256 + k0 + kc);
      const float* p = hb + (size_t)(n0 + row) * 256 + k0 + kc;
      f32x4 v0 = *(const f32x4*)p, v1 = *(const f32x4*)(p + 4);
      b16x8 hv;
      #pragma unroll
      for (int e = 0; e < 4; ++e) { hv[e] = (__bf16)v0[e]; hv[4 + e] = (__bf16)v1[e]; }
      *(b16x8*)&Bt[row][kc] = hv;
    }
    __syncthreads();
    #pragma unroll
    for (int ks = 0; ks < 2; ++ks) {
      b16x8 af[4], bf4[4];
      #pragma unroll
      for (int mi = 0; mi < 4; ++mi) af[mi]  = *(const b16x8*)&At[wr + mi * 16 + m16][ks * 32 + 8 * g];
      #pragma unroll
      for (int ni = 0; ni < 4; ++ni) bf4[ni] = *(const b16x8*)&Bt[wc + ni * 16 + m16][ks * 32 + 8 * g];
      #pragma unroll
      for (int mi = 0; mi < 4; ++mi)
        #pragma unroll
        for (int ni = 0; ni < 4; ++ni)
          acc[mi][ni] = MFMA(af[mi], bf4[ni], acc[mi][ni]);
    }
  }
  #pragma unroll
  for (int mi = 0; mi < 4; ++mi)
    #pragma unroll
    for (int r = 0; r < 4; ++r) {
      int d = m0 + wr + mi * 16 + 4 * g + r;
      float bias = bm[d];
      #pragma unroll
      for (int ni = 0; ni < 4; ++ni) {
        int n = n0 + wc + ni * 16 + m16;
        hmT[(size_t)b * H_ * N_ + (size_t)d * N_ + n] = (__bf16)(acc[mi][ni][r] + bias);
      }
    }
}

// ---------------------------------------------------------------------------
// Flash attention + DTNN message:
//   msg[b,i,:] = tanh( mask_i * softmax_j(q_i·h_j + NEG*(1-mask_j)) @ hm )
// Block = (64 i-rows, batch b); 4 waves of 16 rows; j-tiles of 32 with online
// softmax. Logits in 3-term bf16 split (q and K both hi/lo) for accuracy.
// ---------------------------------------------------------------------------
__global__ __launch_bounds__(256) void k_attn(
    const float* __restrict__ q, const float* __restrict__ h,
    const float* __restrict__ mask, const __bf16* __restrict__ hmT,
    __bf16* __restrict__ msg) {
  __shared__ __bf16 Khi[32][264], Klo[32][264];   // j-tile of K, hi/lo split
  __shared__ __bf16 Plds[4][16][40];              // per-wave P round-trip
  const int tid = threadIdx.x, lane = tid & 63, wave = tid >> 6;
  const int g = lane >> 4, m16 = lane & 15;
  const int b = blockIdx.y, i0 = blockIdx.x * 64;

  // Q fragments in registers (rows i0 + wave*16 + m16), split hi/lo
  const float* qp = q + (size_t)(b * N_ + i0 + wave * 16 + m16) * H_ + 8 * g;
  b16x8 qhi[8], qlo[8];
  #pragma unroll
  for (int kb = 0; kb < 8; ++kb) {
    f32x4 v0 = *(const f32x4*)(qp + kb * 32);
    f32x4 v1 = *(const f32x4*)(qp + kb * 32 + 4);
    #pragma unroll
    for (int e = 0; e < 4; ++e) {
      __bf16 h0 = (__bf16)v0[e], h1 = (__bf16)v1[e];
      qhi[kb][e] = h0; qhi[kb][4 + e] = h1;
      qlo[kb][e]     = (__bf16)(v0[e] - (float)h0);
      qlo[kb][4 + e] = (__bf16)(v1[e] - (float)h1);
    }
  }

  f32x4 o[16] = {};
  float mrun[4], lrun[4];
  #pragma unroll
  for (int r = 0; r < 4; ++r) { mrun[r] = -3.0e38f; lrun[r] = 0.f; }

  const __bf16* hvb = hmT + (size_t)b * H_ * N_;
  const float*  hb  = h   + (size_t)b * N_ * H_;

  for (int jt = 0; jt < 16; ++jt) {
    int j0 = jt * 32;
    __syncthreads();
    { // stage K-tile (32 rows x 256) fp32 -> hi/lo bf16
      int row = tid >> 3, ks0 = (tid & 7) * 32;
      const float* p = hb + (size_t)(j0 + row) * H_ + ks0;
      #pragma unroll
      for (int c2 = 0; c2 < 4; ++c2) {
        f32x4 v0 = *(const f32x4*)(p + c2 * 8);
        f32x4 v1 = *(const f32x4*)(p + c2 * 8 + 4);
        b16x8 hv, lv;
        #pragma unroll
        for (int e = 0; e < 4; ++e) {
          __bf16 h0 = (__bf16)v0[e], h1 = (__bf16)v1[e];
          hv[e] = h0; hv[4 + e] = h1;
          lv[e]     = (__bf16)(v0[e] - (float)h0);
          lv[4 + e] = (__bf16)(v1[e] - (float)h1);
        }
        *(b16x8*)&Khi[row][ks0 + c2 * 8] = hv;
        *(b16x8*)&Klo[row][ks0 + c2 * 8] = lv;
      }
    }
    __syncthreads();

    // S = q · K^T (3-term split), 16 rows x 32 cols per wave
    f32x4 s[2] = {};
    #pragma unroll
    for (int kb = 0; kb < 8; ++kb)
      #pragma unroll
      for (int cf = 0; cf < 2; ++cf) {
        b16x8 kh = *(const b16x8*)&Khi[cf * 16 + m16][kb * 32 + 8 * g];
        b16x8 kl = *(const b16x8*)&Klo[cf * 16 + m16][kb * 32 + 8 * g];
        s[cf] = MFMA(qhi[kb], kh, s[cf]);
        s[cf] = MFMA(qhi[kb], kl, s[cf]);
        s[cf] = MFMA(qlo[kb], kh, s[cf]);
      }
    // column mask
    #pragma unroll
    for (int cf = 0; cf < 2; ++cf) {
      float cm  = mask[b * N_ + j0 + cf * 16 + m16];
      float add = NEGV * (1.f - cm);
      #pragma unroll
      for (int r = 0; r < 4; ++r) s[cf][r] += add;
    }
    // online softmax (rows live in 16-lane groups)
    float p_[2][4];
    #pragma unroll
    for (int r = 0; r < 4; ++r) {
      float mx = fmaxf(s[0][r], s[1][r]);
      #pragma unroll
      for (int off = 1; off < 16; off <<= 1) mx = fmaxf(mx, __shfl_xor(mx, off, 64));
      float mnew  = fmaxf(mrun[r], mx);
      float alpha = __expf(mrun[r] - mnew);
      float ps = 0.f;
      #pragma unroll
      for (int cf = 0; cf < 2; ++cf) {
        float pv = __expf(s[cf][r] - mnew);
        p_[cf][r] = pv; ps += pv;
      }
      #pragma unroll
      for (int off = 1; off < 16; off <<= 1) ps += __shfl_xor(ps, off, 64);
      lrun[r] = lrun[r] * alpha + ps;
      mrun[r] = mnew;
      #pragma unroll
      for (int c2 = 0; c2 < 16; ++c2) o[c2][r] *= alpha;
    }
    // P -> LDS (C-layout) -> A-fragment layout (wave-local round trip)
    #pragma unroll
    for (int cf = 0; cf < 2; ++cf)
      #pragma unroll
      for (int r = 0; r < 4; ++r)
        Plds[wave][4 * g + r][cf * 16 + m16] = (__bf16)p_[cf][r];
    asm volatile("s_waitcnt lgkmcnt(0)" ::: "memory");
    b16x8 pa = *(const b16x8*)&Plds[wave][m16][8 * g];
    // PV: o += P @ hm_tile  (B-frags straight from hmT, k-contiguous)
    #pragma unroll
    for (int c2 = 0; c2 < 16; ++c2) {
      const __bf16* vp = hvb + (size_t)(c2 * 16 + m16) * N_ + j0 + 8 * g;
      b16x8 vv = *(const b16x8*)vp;
      o[c2] = MFMA(pa, vv, o[c2]);
    }
  }

  // epilogue: msg = tanh(row_mask * O / l)
  #pragma unroll
  for (int r = 0; r < 4; ++r) {
    int irow = i0 + wave * 16 + 4 * g + r;
    float rm  = mask[b * N_ + irow];
    float inv = rm / lrun[r];
    #pragma unroll
    for (int c2 = 0; c2 < 16; ++c2) {
      float val = tanhf(o[c2][r] * inv);
      msg[(size_t)(b * N_ + irow) * H_ + c2 * 16 + m16] = (__bf16)val;
    }
  }
}

// ---------------------------------------------------------------------------
// Gates: [z|r]_pre = [msg|h] @ WzrT^T + c_{z|r};  z = sigmoid, rh = sigmoid(r)*h
// Tile 128x128, BK=64, K=512 (k<256: msg bf16; k>=256: h fp32->bf16).
// ---------------------------------------------------------------------------
__global__ __launch_bounds__(256) void k_gemm_zr(
    const __bf16* __restrict__ msg, const float* __restrict__ h,
    const __bf16* __restrict__ WzrT, const float* __restrict__ cz,
    const float* __restrict__ cr, __bf16* __restrict__ z, __bf16* __restrict__ rh) {
  __shared__ __bf16 At[128][72], Bt[128][72];
  const int tid = threadIdx.x, lane = tid & 63, wave = tid >> 6;
  const int g = lane >> 4, m16 = lane & 15;
  const int wr = (wave >> 1) * 64, wc = (wave & 1) * 64;
  const int m0 = blockIdx.y * 128, n0 = blockIdx.x * 128;
  f32x4 acc[4][4] = {};
  for (int k0 = 0; k0 < 512; k0 += 64) {
    __syncthreads();
    #pragma unroll
    for (int i = 0; i < 4; ++i) {
      int c = tid + i * 256;
      int row = c >> 3, kc = (c & 7) * 8;
      if (k0 < 256) {
        *(b16x8*)&At[row][kc] = *(const b16x8*)(msg + (size_t)(m0 + row) * 256 + k0 + kc);
      } else {
        const float* p = h + (size_t)(m0 + row) * 256 + (k0 - 256) + kc;
        f32x4 v0 = *(const f32x4*)p, v1 = *(const f32x4*)(p + 4);
        b16x8 hv;
        #pragma unroll
        for (int e = 0; e < 4; ++e) { hv[e] = (__bf16)v0[e]; hv[4 + e] = (__bf16)v1[e]; }
        *(b16x8*)&At[row][kc] = hv;
      }
      *(b16x8*)&Bt[row][kc] = *(const b16x8*)(WzrT + (size_t)(n0 + row) * 512 + k0 + kc);
    }
    __syncthreads();
    #pragma unroll
    for (int ks = 0; ks < 2; ++ks) {
      b16x8 af[4], bf4[4];
      #pragma unroll
      for (int mi = 0; mi < 4; ++mi) af[mi]  = *(const b16x8*)&At[wr + mi * 16 + m16][ks * 32 + 8 * g];
      #pragma unroll
      for (int ni = 0; ni < 4; ++ni) bf4[ni] = *(const b16x8*)&Bt[wc + ni * 16 + m16][ks * 32 + 8 * g];
      #pragma unroll
      for (int mi = 0; mi < 4; ++mi)
        #pragma unroll
        for (int ni = 0; ni < 4; ++ni)
          acc[mi][ni] = MFMA(af[mi], bf4[ni], acc[mi][ni]);
    }
  }
  #pragma unroll
  for (int mi = 0; mi < 4; ++mi)
    #pragma unroll
    for (int ni = 0; ni < 4; ++ni) {
      int gcol = n0 + wc + ni * 16 + m16;
      #pragma unroll
      for (int r = 0; r < 4; ++r) {
        int grow = m0 + wr + mi * 16 + 4 * g + r;
        int bb = grow >> 9;
        float a = acc[mi][ni][r];
        if (gcol < 256) {
          float v = a + cz[bb * 256 + gcol];
          z[(size_t)grow * 256 + gcol] = (__bf16)(1.f / (1.f + __expf(-v)));
        } else {
          int c2 = gcol - 256;
          float v  = a + cr[bb * 256 + c2];
          float rr = 1.f / (1.f + __expf(-v));
          rh[(size_t)grow * 256 + c2] = (__bf16)(rr * h[(size_t)grow * 256 + c2]);
        }
      }
    }
}

// ---------------------------------------------------------------------------
// h_tilde = tanh([msg|r*h] @ WhcT^T + c_h);  out = (1-z)*h + z*h_tilde
// ---------------------------------------------------------------------------
__global__ __launch_bounds__(256) void k_gemm_ht(
    const __bf16* __restrict__ msg, const __bf16* __restrict__ rh,
    const __bf16* __restrict__ WhcT, const float* __restrict__ ch,
    const __bf16* __restrict__ z, const float* __restrict__ h,
    float* __restrict__ out) {
  __shared__ __bf16 At[128][72], Bt[128][72];
  const int tid = threadIdx.x, lane = tid & 63, wave = tid >> 6;
  const int g = lane >> 4, m16 = lane & 15;
  const int wr = (wave >> 1) * 64, wc = (wave & 1) * 64;
  const int m0 = blockIdx.y * 128, n0 = blockIdx.x * 128;
  f32x4 acc[4][4] = {};
  for (int k0 = 0; k0 < 512; k0 += 64) {
    __syncthreads();
    const __bf16* asrc = (k0 < 256) ? msg : rh;
    int ak = k0 & 255;
    #pragma unroll
    for (int i = 0; i < 4; ++i) {
      int c = tid + i * 256;
      int row = c >> 3, kc = (c & 7) * 8;
      *(b16x8*)&At[row][kc] = *(const b16x8*)(asrc + (size_t)(m0 + row) * 256 + ak + kc);
      *(b16x8*)&Bt[row][kc] = *(const b16x8*)(WhcT + (size_t)(n0 + row) * 512 + k0 + kc);
    }
    __syncthreads();
    #pragma unroll
    for (int ks = 0; ks < 2; ++ks) {
      b16x8 af[4], bf4[4];
      #pragma unroll
      for (int mi = 0; mi < 4; ++mi) af[mi]  = *(const b16x8*)&At[wr + mi * 16 + m16][ks * 32 + 8 * g];
      #pragma unroll
      for (int ni = 0; ni < 4; ++ni) bf4[ni] = *(const b16x8*)&Bt[wc + ni * 16 + m16][ks * 32 + 8 * g];
      #pragma unroll
      for (int mi = 0; mi < 4; ++mi)
        #pragma unroll
        for (int ni = 0; ni < 4; ++ni)
          acc[mi][ni] = MFMA(af[mi], bf4[ni], acc[mi][ni]);
    }
  }
  #pragma unroll
  for (int mi = 0; mi < 4; ++mi)
    #pragma unroll
    for (int ni = 0; ni < 4; ++ni) {
      int gcol = n0 + wc + ni * 16 + m16;
      #pragma unroll
      for (int r = 0; r < 4; ++r) {
        int grow = m0 + wr + mi * 16 + 4 * g + r;
        int bb = grow >> 9;
        size_t oidx = (size_t)grow * 256 + gcol;
        float pre = acc[mi][ni][r] + ch[bb * 256 + gcol];
        float htl = tanhf(pre);
        float zv  = (float)z[oidx];
        float hv  = h[oidx];
        out[oidx] = (1.f - zv) * hv + zv * htl;
      }
    }
}

// ---------------------------------------------------------------------------
extern "C" void kernel_launch(void* const* d_in, const int* in_sizes, int n_in,
                              void* d_out, int out_size, void* d_ws, size_t ws_size,
                              hipStream_t stream) {
  const float* h    = (const float*)d_in[0];
  const float* jets = (const float*)d_in[1];
  const float* mask = (const float*)d_in[2];
  const float* Wa   = (const float*)d_in[3];
  const float* ba   = (const float*)d_in[4];
  const float* Wm   = (const float*)d_in[5];
  const float* bm   = (const float*)d_in[6];
  const float* Wz   = (const float*)d_in[7];
  const float* bz   = (const float*)d_in[8];
  const float* Wr   = (const float*)d_in[9];
  const float* br   = (const float*)d_in[10];
  const float* Wh   = (const float*)d_in[11];
  const float* bh   = (const float*)d_in[12];
  float* out = (float*)d_out;

  char* ws = (char*)d_ws;
  size_t off = 0;
  auto alloc = [&](size_t bytes) -> void* {
    void* p = ws + off;
    off += (bytes + 255) & ~(size_t)255;
    return p;
  };
  float*  q     = (float*) alloc((size_t)ROWS * H_ * 4);   // 64 MiB, aliased by z/rh later
  __bf16* hmT   = (__bf16*)alloc((size_t)B_ * H_ * N_ * 2);
  __bf16* msg   = (__bf16*)alloc((size_t)ROWS * H_ * 2);
  float*  hmean = (float*) alloc((size_t)B_ * H_ * 4);
  float*  cz    = (float*) alloc((size_t)B_ * H_ * 4);
  float*  cr    = (float*) alloc((size_t)B_ * H_ * 4);
  float*  chv   = (float*) alloc((size_t)B_ * H_ * 4);
  __bf16* WaT_hi = (__bf16*)alloc(65536 * 2);
  __bf16* WaT_lo = (__bf16*)alloc(65536 * 2);
  __bf16* WmT    = (__bf16*)alloc(65536 * 2);
  __bf16* WzrT   = (__bf16*)alloc(262144 * 2);
  __bf16* WhcT   = (__bf16*)alloc(131072 * 2);
  // z and rh alias the q buffer: q is dead after k_attn, which runs before k_gemm_zr.
  __bf16* z  = (__bf16*)q;
  __bf16* rh = (__bf16*)((char*)q + (size_t)ROWS * H_ * 2);
  if (off > ws_size) return;  // workspace insufficient (will fail validation loudly)

  k_prep   <<<2048, 256, 0, stream>>>(Wa, Wm, Wz, Wr, Wh, WaT_hi, WaT_lo, WmT, WzrT, WhcT);
  k_hmean  <<<B_, H_, 0, stream>>>(h, hmean);
  k_cvec   <<<B_, H_, 0, stream>>>(hmean, jets, Wz, Wr, Wh, bz, br, bh, cz, cr, chv);
  k_gemm_q <<<dim3(2, 512), 256, 0, stream>>>(h, WaT_hi, WaT_lo, ba, q);
  k_gemm_hmT<<<dim3(8, 128), 256, 0, stream>>>(h, WmT, bm, hmT);
  k_attn   <<<dim3(8, 128), 256, 0, stream>>>(q, h, mask, hmT, msg);
  k_gemm_zr<<<dim3(4, 512), 256, 0, stream>>>(msg, h, WzrT, cz, cr, z, rh);
  k_gemm_ht<<<dim3(2, 512), 256, 0, stream>>>(msg, rh, WhcT, chv, z, h, out);
}